// Round 1
// baseline (374.462 us; speedup 1.0000x reference)
//
#include <hip/hip_runtime.h>

typedef _Float16 half8 __attribute__((ext_vector_type(8)));
typedef float floatx4 __attribute__((ext_vector_type(4)));

constexpr int IN_F  = 8192;
constexpr int OUT_F = 8192;
constexpr int NCOL  = 16;

constexpr int CHUNKS  = 32;                      // K-split factor
constexpr int CHUNK_K = IN_F / CHUNKS;           // 256
constexpr int STEPS   = CHUNK_K / 32;            // 8 MFMA k-steps per chunk
constexpr int RB      = 4;                       // 16-row tiles per wave
constexpr int WPB     = 4;                       // waves per block (256 thr)
constexpr int ROWS_PER_WAVE = RB * 16;           // 64
constexpr int RGROUPS = OUT_F / ROWS_PER_WAVE;   // 128
constexpr int NBLOCKS = CHUNKS * RGROUPS / WPB;  // 1024

// D = W @ x, W fed as MFMA A-operand (16 rows), x as B (16 cols), fp32 acc.
// Layouts (gfx950, HW-verified): A[m=lane&15][k=quad*8+j],
// B[k=quad*8+j][n=lane&15], C/D: col=lane&15, row=quad*4+reg.
__global__ __launch_bounds__(256, 4)
void lq_mfma_kernel(const float* __restrict__ x,
                    const void* __restrict__ wraw,
                    const float* __restrict__ scaler,
                    float* __restrict__ out)
{
    const int tid   = threadIdx.x;
    const int lane  = tid & 63;
    const int wv    = tid >> 6;
    const int W     = blockIdx.x * WPB + wv;     // 0..4095
    const int chunk = W & (CHUNKS - 1);          // k-chunk id
    const int rg    = W / CHUNKS;                // row-group id (64 rows)
    const int k0    = chunk * CHUNK_K;
    const int m     = lane & 15;                 // A row-in-tile == C col
    const int quad  = lane >> 4;

    // ---- dtype probe: int32-materialized weights vs raw int8 (wave-uniform) ----
    const int* wi = (const int*)wraw;
    bool w_is_i32 = true;
    #pragma unroll
    for (int i = 0; i < 16; ++i) {
        int v = wi[i];
        w_is_i32 = w_is_i32 && (v >= -128) && (v <= 127);
    }

    const float s = *scaler;

    // ---- B fragments: resident in regs for the whole kernel (32 VGPRs) ----
    half8 bf[STEPS];
    #pragma unroll
    for (int st = 0; st < STEPS; ++st) {
        #pragma unroll
        for (int j = 0; j < 8; ++j) {
            const int k = k0 + st * 32 + quad * 8 + j;
            bf[st][j] = (_Float16)x[k * NCOL + m];
        }
    }

    if (w_is_i32) {
        // ---- path A: weights are int32 (268 MB stream) ----
        const int* wp = (const int*)wraw;
        #pragma unroll 1
        for (int r = 0; r < RB; ++r) {
            const int row = rg * ROWS_PER_WAVE + r * 16 + m;
            const int* wrow = wp + (size_t)row * IN_F + k0 + quad * 8;
            floatx4 acc = {0.f, 0.f, 0.f, 0.f};
            #pragma unroll
            for (int st = 0; st < STEPS; ++st) {
                half8 af;
                #pragma unroll
                for (int j = 0; j < 8; ++j)
                    af[j] = (_Float16)wrow[st * 32 + j];   // 2x dwordx4, coalesced
                acc = __builtin_amdgcn_mfma_f32_16x16x32_f16(af, bf[st], acc, 0, 0, 0);
            }
            const int orow = rg * ROWS_PER_WAVE + r * 16 + quad * 4;
            #pragma unroll
            for (int g = 0; g < 4; ++g)
                atomicAdd(&out[(orow + g) * NCOL + m], acc[g] * s);
        }
    } else {
        // ---- path B: weights are raw int8 (64 MB stream) ----
        const signed char* wp = (const signed char*)wraw;
        #pragma unroll 1
        for (int r = 0; r < RB; ++r) {
            const int row = rg * ROWS_PER_WAVE + r * 16 + m;
            const signed char* wrow = wp + (size_t)row * IN_F + k0 + quad * 8;
            floatx4 acc = {0.f, 0.f, 0.f, 0.f};
            #pragma unroll
            for (int st = 0; st < STEPS; ++st) {
                const uint2 u = *(const uint2*)(wrow + st * 32); // 8 int8, coalesced
                half8 af;
                #pragma unroll
                for (int j = 0; j < 4; ++j) {
                    af[j]     = (_Float16)(int)(signed char)(u.x >> (8 * j));
                    af[j + 4] = (_Float16)(int)(signed char)(u.y >> (8 * j));
                }
                acc = __builtin_amdgcn_mfma_f32_16x16x32_f16(af, bf[st], acc, 0, 0, 0);
            }
            const int orow = rg * ROWS_PER_WAVE + r * 16 + quad * 4;
            #pragma unroll
            for (int g = 0; g < 4; ++g)
                atomicAdd(&out[(orow + g) * NCOL + m], acc[g] * s);
        }
    }
}

extern "C" void kernel_launch(void* const* d_in, const int* in_sizes, int n_in,
                              void* d_out, int out_size, void* d_ws, size_t ws_size,
                              hipStream_t stream)
{
    const float* x      = (const float*)d_in[0];
    const void*  w      = d_in[1];
    const float* scaler = (const float*)d_in[2];
    float*       out    = (float*)d_out;

    // K-split partials accumulate via atomicAdd -> zero the output first.
    hipMemsetAsync(out, 0, (size_t)OUT_F * NCOL * sizeof(float), stream);
    lq_mfma_kernel<<<NBLOCKS, 256, 0, stream>>>(x, w, scaler, out);
}